// Round 4
// baseline (99.995 us; speedup 1.0000x reference)
//
#include <hip/hip_runtime.h>

// SpaceToDepth bs=2: x0 (16,64,256,256) f32 -> y (16,256,128,128) f32, plus x1 (16,) passthrough.
// y[b, hin*128 + win*64 + c, ho, wo] = x0[b, c, 2*ho + hin, 2*wo + win]
// d_out = [ y flat (67,108,864 floats) | x1 (16 floats) ]
//
// R4: LDS-staged, BOTH sides max-contiguous.
// Block tile = one (b,c), 16 consecutive input rows (16 KB contiguous read).
// Deinterleave through LDS (A=evens, B=odds), then write four 4 KB contiguous
// output segments (8 consecutive ho rows in each of channels d, d+64, d+128, d+192 pattern).
// All LDS ops are contiguous-per-half-wave b128 -> zero bank conflicts.

typedef float v4f __attribute__((ext_vector_type(4)));

constexpr long long Y_ELEMS = 67108864;   // 16*256*128*128

__global__ void __launch_bounds__(256) s2d_kernel(const v4f* __restrict__ in,
                                                  const float* __restrict__ x1,
                                                  v4f* __restrict__ out) {
    __shared__ float A[16 * 128];   // evens: A[hl][wo] -> output row (hin=hl&1, ho=ho0+(hl>>1)), win=0
    __shared__ float B[16 * 128];   // odds : win=1

    int T = blockIdx.x;             // 16384 tiles
    int hblk = T & 15;              // which 16-row band of H
    int c    = (T >> 4) & 63;
    int b    = T >> 10;

    long long tile_base4 = (((long long)(b * 64 + c)) * 256 + hblk * 16) * 64;  // float4 idx

    int tid = threadIdx.x;

    // Phase 1: contiguous 16 KB read, deinterleave into LDS.
    // pair-unit p (0..511): hl = p>>5, wp = p&31; reads input float4s 2p, 2p+1.
    #pragma unroll
    for (int it = 0; it < 2; ++it) {
        int p  = tid + it * 256;
        int hl = p >> 5;
        int wp = p & 31;
        long long i4 = tile_base4 + (long long)hl * 64 + (wp << 1);
        v4f v0 = in[i4];
        v4f v1 = in[i4 + 1];
        v4f s0 = {v0.x, v0.z, v1.x, v1.z};   // evens -> A[hl][4*wp..+3]
        v4f s1 = {v0.y, v0.w, v1.y, v1.w};   // odds  -> B[hl][4*wp..+3]
        *reinterpret_cast<v4f*>(&A[hl * 128 + (wp << 2)]) = s0;
        *reinterpret_cast<v4f*>(&B[hl * 128 + (wp << 2)]) = s1;
    }

    __syncthreads();

    // Phase 2: four 4 KB contiguous output segments.
    // seg s: win = s>>1 (A/B), hin = s&1. d = hin*128 + win*64 + c.
    int s   = tid >> 6;
    int l   = tid & 63;
    int win = s >> 1;
    int hin = s & 1;
    int d   = hin * 128 + win * 64 + c;
    int ho0 = hblk * 8;

    const float* buf = win ? B : A;
    long long obase4 = (((long long)(b * 256 + d)) * 128 + ho0) * 32;  // float4 idx

    #pragma unroll
    for (int it = 0; it < 4; ++it) {
        int f    = l + it * 64;       // 0..255 within segment
        int ho_l = f >> 5;
        int wo4  = f & 31;
        v4f v = *reinterpret_cast<const v4f*>(&buf[(ho_l * 2 + hin) * 128 + (wo4 << 2)]);
        out[obase4 + f] = v;
    }

    // x1 passthrough (16 floats) appended after y
    if (blockIdx.x == 0 && tid < 16) {
        ((float*)out)[Y_ELEMS + tid] = x1[tid];
    }
}

extern "C" void kernel_launch(void* const* d_in, const int* in_sizes, int n_in,
                              void* d_out, int out_size, void* d_ws, size_t ws_size,
                              hipStream_t stream) {
    const v4f*   x0 = (const v4f*)d_in[0];
    const float* x1 = (const float*)d_in[1];
    v4f* out = (v4f*)d_out;

    const int block = 256;
    const int grid  = 16384;   // 16 b * 64 c * 16 h-bands
    s2d_kernel<<<grid, block, 0, stream>>>(x0, x1, out);
}

// Round 5
// 93.919 us; speedup vs baseline: 1.0647x; 1.0647x over previous
//
#include <hip/hip_runtime.h>

// SpaceToDepth bs=2: x0 (16,64,256,256) f32 -> y (16,256,128,128) f32, plus x1 (16,) passthrough.
// y[b, h_in*128 + w_in*64 + c, ho, wo] = x0[b, c, 2*ho + h_in, 2*wo + w_in]
// d_out = [ y flat (67,108,864 floats) | x1 (16 floats) ]
//
// FINAL (revert to R1, the best-measured variant: 94.0 us, 5.71 TB/s = 91% of
// the 6.29 TB/s measured copy ceiling). Ablation ladder:
//   R1 float4 read -> 2x float2 store           94.0 us   <== best
//   R2 32B/lane + nontemporal                   95.0 us
//   R3 output-contiguous mapping                97.1 us
//   R4 LDS-staged, both sides contiguous       100.0 us
// Traffic is exactly the mandatory 512 MiB both ways; the ~9% gap to pure-copy
// is the structural cost of the 2-plane interleaved write stream. Roofline.

constexpr int Bn = 16, Cn = 64, Hn = 256, Wn = 256;
constexpr int HOn = Hn / 2, WOn = Wn / 2;              // 128, 128
constexpr long long Y_ELEMS = (long long)Bn * (4 * Cn) * HOn * WOn;  // 67,108,864
constexpr long long N_F4 = (long long)Bn * Cn * Hn * Wn / 4;         // 16,777,216 float4 units
constexpr long long WIN1_OFF = (long long)Cn * HOn * WOn;            // 1,048,576 (d += 64)

__global__ void __launch_bounds__(256) s2d_kernel(const float4* __restrict__ in,
                                                  const float* __restrict__ x1,
                                                  float* __restrict__ out) {
    long long t = (long long)blockIdx.x * blockDim.x + threadIdx.x;  // one float4 per thread

    // input flat float4 index t decomposes as (b, c, h, w4) with W4=64, H=256, C=64
    int w4 = (int)(t & 63);          // 4*w4 = input w base
    int h  = (int)((t >> 6) & 255);
    int c  = (int)((t >> 14) & 63);
    int b  = (int)(t >> 20);

    float4 v = in[t];                // fully coalesced 16B/lane

    int ho  = h >> 1;
    int hin = h & 1;
    int wo  = w4 << 1;               // even -> float2 stores are 8B-aligned

    // w_in = 0 channel: d = hin*128 + c ; w_in = 1 channel: d += 64
    long long base = ((((long long)b * 256 + (long long)(hin * 128 + c)) * HOn) + ho) * WOn + wo;

    *reinterpret_cast<float2*>(out + base)            = make_float2(v.x, v.z);
    *reinterpret_cast<float2*>(out + base + WIN1_OFF) = make_float2(v.y, v.w);

    // x1 passthrough (16 floats) appended after y
    if (blockIdx.x == 0 && threadIdx.x < 16) {
        out[Y_ELEMS + threadIdx.x] = x1[threadIdx.x];
    }
}

extern "C" void kernel_launch(void* const* d_in, const int* in_sizes, int n_in,
                              void* d_out, int out_size, void* d_ws, size_t ws_size,
                              hipStream_t stream) {
    const float4* x0 = (const float4*)d_in[0];
    const float*  x1 = (const float*)d_in[1];
    float* out = (float*)d_out;

    const int block = 256;
    const long long grid = N_F4 / block;  // 65,536 blocks, exact
    s2d_kernel<<<(int)grid, block, 0, stream>>>(x0, x1, out);
}